// Round 5
// baseline (177.681 us; speedup 1.0000x reference)
//
#include <hip/hip_runtime.h>
#include <math.h>

// Problem constants (B=1)
#define TT   192      // sequence length T
#define HH   1024     // hidden H
#define NHH  16       // heads
#define HD   64       // head dim
#define H3   3072     // 3*H
#define QKS  2048     // Q|K buffer row stride (V lives transposed in Vt)
#define VTS  200      // Vt row stride in shorts (padded, 192 used)
#define LN_EPS 1e-5f

// -------------------------------------------------------------------------
// build_edges is numerically dead: edges=softmax(scores,-1) is consumed only
// as edges.sum(-1)==1.0 -> ew constant along attention softmax axis ->
// softmax shift invariance -> output == 2 layers of plain MHA + LN + residual.
// -------------------------------------------------------------------------

typedef __attribute__((ext_vector_type(4))) float floatx4;
typedef __attribute__((ext_vector_type(8))) short short8;

static __device__ inline unsigned short f2bf(float f) {
    union { float f; unsigned u; } v; v.f = f;
    return (unsigned short)((v.u + 0x7fffu + ((v.u >> 16) & 1u)) >> 16);  // RNE
}

// fused fp32->bf16 of the three sources in one dispatch
__global__ __launch_bounds__(256) void cvt3(const float* __restrict__ a, int na4,
                                            const float* __restrict__ b, int nb4,
                                            const float* __restrict__ c, int nc4,
                                            unsigned short* __restrict__ da,
                                            unsigned short* __restrict__ db,
                                            unsigned short* __restrict__ dc)
{
    int j = blockIdx.x * 256 + threadIdx.x;
    const float* s; unsigned short* d;
    if (j < na4)                 { s = a; d = da; }
    else if ((j -= na4) < nb4)   { s = b; d = db; }
    else if ((j -= nb4) < nc4)   { s = c; d = dc; }
    else return;
    float4 v = ((const float4*)s)[j];
    ushort4 o;
    o.x = f2bf(v.x); o.y = f2bf(v.y); o.z = f2bf(v.z); o.w = f2bf(v.w);
    ((ushort4*)d)[j] = o;
}

#define GLD(gp, lp) __builtin_amdgcn_global_load_lds( \
    (const __attribute__((address_space(1))) void*)(gp), \
    (__attribute__((address_space(3))) void*)(lp), 16, 0, 0)

// Split-K GEMM partial: P[z][M][N] = A[:, z*KS..) @ B[:, z*KS..)^T  (bf16 in,
// fp32 partial out, no bias). Tile 64x64, ONE staging shot of KS columns:
// single vmcnt drain per block; latency overlapped across co-resident blocks
// (grid >> 256). XOR swizzle (phys chunk = logical ^ (row&7)) keeps both the
// lane-contiguous global_load_lds staging and ds_read_b128 frag reads
// conflict-free with unpadded rows.
template <int KS>
__global__ __launch_bounds__(256) void gemm_splitk(const unsigned short* __restrict__ A,
                                                   const unsigned short* __restrict__ Bw,
                                                   float* __restrict__ P,
                                                   int M, int N, int K)
{
    constexpr int LPR = KS / 8;      // 16-B chunks (lanes) per row
    constexpr int RPG = 512 / KS;    // rows covered by one 1-KB GLD
    constexpr int NG  = KS / 32;     // GLDs per wave per matrix
    __shared__ __align__(16) unsigned short As[64 * KS];
    __shared__ __align__(16) unsigned short Bs[64 * KS];
    const int tid  = threadIdx.x;
    const int w    = tid >> 6;
    const int lane = tid & 63;
    const int quad = lane >> 4;
    const int l16  = lane & 15;
    const int m0 = blockIdx.y * 64;
    const int n0 = blockIdx.x * 64;
    const int k0 = blockIdx.z * KS;

    const int rin = lane / LPR;      // row within a GLD
    const int cl  = lane % LPR;      // logical chunk slot

    #pragma unroll
    for (int j = 0; j < NG; ++j) {
        const int g   = w * NG + j;
        const int row = g * RPG + rin;
        const int ch  = cl ^ (row & 7);
        GLD(A  + (size_t)(m0 + row) * K + k0 + ch * 8, As + g * 512);
        GLD(Bw + (size_t)(n0 + row) * K + k0 + ch * 8, Bs + g * 512);
    }
    __syncthreads();    // the single vmcnt drain

    floatx4 acc[4] = {};
    #pragma unroll
    for (int kc = 0; kc < KS / 32; ++kc) {
        const int s = (kc * 4 + quad) ^ (l16 & 7);
        short8 af = *(const short8*)&As[(w * 16 + l16) * KS + s * 8];
        #pragma unroll
        for (int nt = 0; nt < 4; ++nt) {
            short8 bf = *(const short8*)&Bs[(nt * 16 + l16) * KS + s * 8];
            acc[nt] = __builtin_amdgcn_mfma_f32_16x16x32_bf16(af, bf, acc[nt], 0, 0, 0);
        }
    }

    float* Pz = P + (size_t)blockIdx.z * M * N;
    #pragma unroll
    for (int nt = 0; nt < 4; ++nt) {
        const int col = n0 + nt * 16 + l16;
        #pragma unroll
        for (int r = 0; r < 4; ++r)
            Pz[(size_t)(m0 + w * 16 + quad * 4 + r) * N + col] = acc[nt][r];
    }
}

// Sum 4 qkv partials + bias -> bf16. Cols < 2H go row-major into qkvQK
// (stride QKS); V cols (>= 2H) are transposed via LDS into Vt[d][t].
__global__ __launch_bounds__(256) void qkv_finish(const float* __restrict__ P,
                                                  const float* __restrict__ bias,
                                                  unsigned short* __restrict__ qkvQK,
                                                  unsigned short* __restrict__ Vt)
{
    __shared__ unsigned short Tl[64][65];
    const int c0 = blockIdx.x * 64;
    const int t0 = blockIdx.y * 64;
    const int tid  = threadIdx.x;
    const int c_in = tid & 63;
    const int tb   = tid >> 6;
    const float bz = bias[c0 + c_in];
    const bool isV = (c0 >= 2 * HH);

    #pragma unroll
    for (int i = 0; i < 16; ++i) {
        const int t_in = tb + 4 * i;
        const size_t idx = (size_t)(t0 + t_in) * H3 + c0 + c_in;
        float v = P[idx] + P[(size_t)TT * H3 + idx]
                + P[2 * (size_t)TT * H3 + idx] + P[3 * (size_t)TT * H3 + idx] + bz;
        if (!isV) qkvQK[(size_t)(t0 + t_in) * QKS + c0 + c_in] = f2bf(v);
        else      Tl[c_in][t_in] = f2bf(v);
    }
    if (!isV) return;
    __syncthreads();
    const int t_out = tid & 63;
    #pragma unroll
    for (int i = 0; i < 16; ++i) {
        const int c_out = tb + 4 * i;
        Vt[(size_t)(c0 - 2 * HH + c_out) * VTS + t0 + t_out] = Tl[c_out][t_out];
    }
}

// Fused attention: one block (256 thr) per (head, 64-query tile).
__global__ __launch_bounds__(256) void attn_fused(const unsigned short* __restrict__ qkv,
                                                  const unsigned short* __restrict__ VtG,
                                                  unsigned short* __restrict__ Oout)
{
    __shared__ __align__(16) unsigned short Qs[64 * 64];     //  8 KB swizzled
    __shared__ __align__(16) unsigned short Ks[192 * 64];    // 24 KB swizzled
    __shared__ __align__(16) unsigned short Vts[64 * VTS];   // 25 KB flat copy
    __shared__ __align__(16) unsigned short Ps[64 * VTS];    // 25 KB padded

    const int h  = blockIdx.x;
    const int q0 = blockIdx.y * 64;
    const int tid  = threadIdx.x;
    const int w    = tid >> 6;
    const int lane = tid & 63;
    const int quad = lane >> 4;
    const int l16  = lane & 15;

    const int rin = lane >> 3;          // 0..7 row within an 8-row GLD
    const int ch8 = (lane & 7) ^ rin;   // swizzled source chunk

    // ---- stage Q (8 GLDs), K (24 GLDs), Vt (25 flat GLDs) ----
    #pragma unroll
    for (int j = 0; j < 2; ++j) {
        const int g = w * 2 + j;
        GLD(qkv + (size_t)(q0 + g * 8 + rin) * QKS + h * HD + ch8 * 8, Qs + g * 512);
    }
    #pragma unroll
    for (int j = 0; j < 6; ++j) {
        const int g = w * 6 + j;
        GLD(qkv + (size_t)(g * 8 + rin) * QKS + HH + h * HD + ch8 * 8, Ks + g * 512);
    }
    #pragma unroll
    for (int j = 0; j < 7; ++j) {
        const int g = w * 7 + j;                       // 0..27
        if (g < 25)                                    // 64*VTS*2 B = 25 KiB
            GLD(VtG + (size_t)h * HD * VTS + g * 512 + lane * 8, Vts + g * 512);
    }
    __syncthreads();

    // ---- S = Q K^T (wave w owns q rows w*16..w*16+15) ----
    floatx4 accs[12] = {};
    #pragma unroll
    for (int kc = 0; kc < 2; ++kc) {
        const int s = (kc * 4 + quad) ^ (l16 & 7);
        short8 af = *(const short8*)&Qs[(w * 16 + l16) * 64 + s * 8];
        #pragma unroll
        for (int nt = 0; nt < 12; ++nt) {
            short8 bf = *(const short8*)&Ks[(nt * 16 + l16) * 64 + s * 8];
            accs[nt] = __builtin_amdgcn_mfma_f32_16x16x32_bf16(af, bf, accs[nt], 0, 0, 0);
        }
    }

    // ---- softmax over 192 keys (12 frags x 16 lanes), scale 1/8 ----
    float invr[4];
    #pragma unroll
    for (int r = 0; r < 4; ++r) {
        float m = accs[0][r];
        #pragma unroll
        for (int nt = 1; nt < 12; ++nt) m = fmaxf(m, accs[nt][r]);
        #pragma unroll
        for (int off = 1; off < 16; off <<= 1) m = fmaxf(m, __shfl_xor(m, off));
        float sum = 0.f;
        #pragma unroll
        for (int nt = 0; nt < 12; ++nt) {
            const float p = __expf((accs[nt][r] - m) * 0.125f);
            accs[nt][r] = p;
            sum += p;
        }
        #pragma unroll
        for (int off = 1; off < 16; off <<= 1) sum += __shfl_xor(sum, off);
        invr[r] = 1.f / sum;
        const int row = w * 16 + quad * 4 + r;
        #pragma unroll
        for (int nt = 0; nt < 12; ++nt)
            Ps[row * VTS + nt * 16 + l16] = f2bf(accs[nt][r]);
    }
    __syncthreads();

    // ---- O = P V  (contract over keys; Vt rows are d, cols are keys) ----
    floatx4 acco[4] = {};
    #pragma unroll
    for (int kc = 0; kc < 6; ++kc) {
        short8 af = *(const short8*)&Ps[(w * 16 + l16) * VTS + kc * 32 + quad * 8];
        #pragma unroll
        for (int nt = 0; nt < 4; ++nt) {
            short8 bf = *(const short8*)&Vts[(nt * 16 + l16) * VTS + kc * 32 + quad * 8];
            acco[nt] = __builtin_amdgcn_mfma_f32_16x16x32_bf16(af, bf, acco[nt], 0, 0, 0);
        }
    }

    #pragma unroll
    for (int nt = 0; nt < 4; ++nt) {
        const int d = h * HD + nt * 16 + l16;
        #pragma unroll
        for (int r = 0; r < 4; ++r) {
            const int q = q0 + w * 16 + quad * 4 + r;
            Oout[(size_t)q * HH + d] = f2bf(acco[nt][r] * invr[r]);
        }
    }
}

// xout = xin + LN(sum_8 P + bias)*g + b ; dual write fp32 + bf16 (block/row)
__global__ __launch_bounds__(256) void ln_residual8(const float* __restrict__ P,
                                                    const float* __restrict__ bias,
                                                    const float* __restrict__ xin,
                                                    const float* __restrict__ g,
                                                    const float* __restrict__ b,
                                                    float* __restrict__ xout,
                                                    unsigned short* __restrict__ xout_bf)
{
    const int row = blockIdx.x;
    const int tid = threadIdx.x;
    const size_t base = (size_t)row * HH + tid * 4;

    float4 v = *(const float4*)&bias[tid * 4];
    #pragma unroll
    for (int z = 0; z < 8; ++z) {
        const float4 p = *(const float4*)&P[(size_t)z * TT * HH + base];
        v.x += p.x; v.y += p.y; v.z += p.z; v.w += p.w;
    }

    float s  = v.x + v.y + v.z + v.w;
    float sq = v.x * v.x + v.y * v.y + v.z * v.z + v.w * v.w;
    #pragma unroll
    for (int off = 32; off > 0; off >>= 1) {
        s  += __shfl_down(s,  off);
        sq += __shfl_down(sq, off);
    }
    __shared__ float ws[4], wq[4];
    const int wave = tid >> 6;
    if ((tid & 63) == 0) { ws[wave] = s; wq[wave] = sq; }
    __syncthreads();
    float ts = 0.f, tq = 0.f;
    #pragma unroll
    for (int w = 0; w < 4; ++w) { ts += ws[w]; tq += wq[w]; }

    const float mean = ts * (1.f / HH);
    const float var  = tq * (1.f / HH) - mean * mean;
    const float r    = rsqrtf(var + LN_EPS);

    const float4 xi = *(const float4*)&xin[base];
    const float4 gg = *(const float4*)&g[tid * 4];
    const float4 bb = *(const float4*)&b[tid * 4];
    float4 o;
    o.x = xi.x + (v.x - mean) * r * gg.x + bb.x;
    o.y = xi.y + (v.y - mean) * r * gg.y + bb.y;
    o.z = xi.z + (v.z - mean) * r * gg.z + bb.z;
    o.w = xi.w + (v.w - mean) * r * gg.w + bb.w;
    *(float4*)&xout[base] = o;
    ushort4 ob;
    ob.x = f2bf(o.x); ob.y = f2bf(o.y); ob.z = f2bf(o.z); ob.w = f2bf(o.w);
    *(ushort4*)&xout_bf[base] = ob;
}

extern "C" void kernel_launch(void* const* d_in, const int* in_sizes, int n_in,
                              void* d_out, int out_size, void* d_ws, size_t ws_size,
                              hipStream_t stream)
{
    const float* nodes     = (const float*)d_in[0];
    const float* mha_in_w  = (const float*)d_in[14];   // [2, 3H, H]
    const float* mha_in_b  = (const float*)d_in[15];   // [2, 3H]
    const float* mha_out_w = (const float*)d_in[16];   // [2, H, H]
    const float* mha_out_b = (const float*)d_in[17];   // [2, H]
    const float* mha_ln_g  = (const float*)d_in[18];   // [2, H]
    const float* mha_ln_b  = (const float*)d_in[19];   // [2, H]
    float* out = (float*)d_out;

    // ---- ws carve (bf16 region then fp32 region; all 16-B aligned) ----
    unsigned short* u = (unsigned short*)d_ws;
    unsigned short* bf_inW   = u;  u += 2 * H3 * HH;
    unsigned short* bf_outW  = u;  u += 2 * HH * HH;
    unsigned short* bf_nodes = u;  u += TT * HH;
    unsigned short* bf_x1    = u;  u += TT * HH;
    unsigned short* bf_qk    = u;  u += TT * QKS;       // Q|K only
    unsigned short* bf_o     = u;  u += TT * HH;
    unsigned short* Vt       = u;  u += HH * VTS;       // [1024][200] bf16
    float* f = (float*)u;
    float* Pqkv  = f;  f += 4 * TT * H3;                // 9.4 MB partials
    float* Pproj = f;  f += 8 * TT * HH;                // 6.3 MB partials
    float* x1    = f;  f += TT * HH;

    // ---- one-time fp32 -> bf16 (in_w | out_w | nodes) in one dispatch ----
    {
        const int na4 = (2 * H3 * HH) / 4;
        const int nb4 = (2 * HH * HH) / 4;
        const int nc4 = (TT * HH) / 4;
        const int tot = na4 + nb4 + nc4;
        cvt3<<<(tot + 255) / 256, 256, 0, stream>>>(
            mha_in_w, na4, mha_out_w, nb4, nodes, nc4, bf_inW, bf_outW, bf_nodes);
    }

    const float* x_f = nodes;
    const unsigned short* x_bf = bf_nodes;
    for (int l = 0; l < 2; ++l) {
        float* xout = (l == 0) ? x1 : out;

        // qkv: [192,3072] = x @ W^T, split-K=4 -> 576 blocks
        gemm_splitk<256><<<dim3(H3 / 64, TT / 64, 4), 256, 0, stream>>>(
            x_bf, bf_inW + (size_t)l * H3 * HH, Pqkv, TT, H3, HH);

        qkv_finish<<<dim3(H3 / 64, TT / 64), 256, 0, stream>>>(
            Pqkv, mha_in_b + l * H3, bf_qk, Vt);

        attn_fused<<<dim3(NHH, TT / 64), 256, 0, stream>>>(bf_qk, Vt, bf_o);

        // out-proj: [192,1024] = o @ W^T, split-K=8 -> 384 blocks
        gemm_splitk<128><<<dim3(HH / 64, TT / 64, 8), 256, 0, stream>>>(
            bf_o, bf_outW + (size_t)l * HH * HH, Pproj, TT, HH, HH);

        ln_residual8<<<TT, 256, 0, stream>>>(
            Pproj, mha_out_b + l * HH, x_f, mha_ln_g + l * HH, mha_ln_b + l * HH,
            xout, bf_x1);

        x_f = xout;
        x_bf = bf_x1;
    }
}